// Round 6
// baseline (696.525 us; speedup 1.0000x reference)
//
#include <hip/hip_runtime.h>
#include <hip/hip_bf16.h>

typedef unsigned int uint;
typedef unsigned short ushort;
typedef __bf16 bf16x8 __attribute__((ext_vector_type(8)));
typedef float f32x4 __attribute__((ext_vector_type(4)));
typedef unsigned short u16x2 __attribute__((ext_vector_type(2)));

#define T_TOK 1024
#define HDIM 2880
#define IDIM 2880
#define NEXP 8
#define GU 5760
#define QK1 1440
#define SG1 90
#define QK2 1440
#define SG2 90
#define MAXR 2048
#define NK 45
#define BM 320

#define ZROW_OFF 98304u
#define HB_OFF 131072u
#define GATED_OFF_PRE 6029312u              // HB_OFF + 1024*2880*2
#define WS_NEED (GATED_OFF_PRE + (size_t)MAXR * IDIM * 2)

// T2 swizzle (proven conflict-free in R3: SQ_LDS_BANK_CONFLICT = 0).
static __device__ __forceinline__ int ls(int row, int c) {
  return (row << 6) + (((c ^ row) & 7) << 3);
}

static __device__ __forceinline__ uint pkadd16(uint a, uint b) {
  u16x2 x = __builtin_bit_cast(u16x2, a);
  u16x2 y = __builtin_bit_cast(u16x2, b);
  u16x2 r = x + y;
  return __builtin_bit_cast(uint, r);
}

// Decode 4 fp4-pair bytes (one byte per int32, packed into P) into 4 dwords of
// 2×bf16 (low nibble = even k first), E8M0 scale fused as exponent add (exact).
static __device__ __forceinline__ void decode8(uint P, uint sAdd2, uint out[4]) {
  uint L  = P & 0x0F0F0F0Fu;
  uint Hh = (P >> 4) & 0x0F0F0F0Fu;
  uint Lm = L & 0x07070707u,  Hm = Hh & 0x07070707u;
  uint Lsg = (L & 0x08080808u) << 4, Hsg = (Hh & 0x08080808u) << 4;
  uint hiL = __builtin_amdgcn_perm(0x40404040u, 0x3F3F3F00u, Lm) | Lsg;
  uint hiH = __builtin_amdgcn_perm(0x40404040u, 0x3F3F3F00u, Hm) | Hsg;
  uint loL = __builtin_amdgcn_perm(0xC0804000u, 0xC0800000u, Lm);
  uint loH = __builtin_amdgcn_perm(0xC0804000u, 0xC0800000u, Hm);
  uint mL  = __builtin_amdgcn_perm(0xFFFFFFFFu, 0xFFFFFF00u, Lm);
  uint mH  = __builtin_amdgcn_perm(0xFFFFFFFFu, 0xFFFFFF00u, Hm);
  uint pL01 = __builtin_amdgcn_perm(hiL, loL, 0x05010400u);
  uint pL23 = __builtin_amdgcn_perm(hiL, loL, 0x07030602u);
  uint pH01 = __builtin_amdgcn_perm(hiH, loH, 0x05010400u);
  uint pH23 = __builtin_amdgcn_perm(hiH, loH, 0x07030602u);
  uint aL01 = pkadd16(pL01, sAdd2 & __builtin_amdgcn_perm(mL, mL, 0x01010000u));
  uint aL23 = pkadd16(pL23, sAdd2 & __builtin_amdgcn_perm(mL, mL, 0x03030202u));
  uint aH01 = pkadd16(pH01, sAdd2 & __builtin_amdgcn_perm(mH, mH, 0x01010000u));
  uint aH23 = pkadd16(pH23, sAdd2 & __builtin_amdgcn_perm(mH, mH, 0x03030202u));
  out[0] = __builtin_amdgcn_perm(aH01, aL01, 0x05040100u);
  out[1] = __builtin_amdgcn_perm(aH01, aL01, 0x07060302u);
  out[2] = __builtin_amdgcn_perm(aH23, aL23, 0x05040100u);
  out[3] = __builtin_amdgcn_perm(aH23, aL23, 0x07060302u);
}

static __device__ __forceinline__ uint packbf2(float a, float b) {
  ushort ua = __builtin_bit_cast(ushort, __float2bfloat16(a));
  ushort ub = __builtin_bit_cast(ushort, __float2bfloat16(b));
  return (uint)ua | ((uint)ub << 16);
}

#define SFENCE() __builtin_amdgcn_sched_barrier(0)
#define SBAR() do { SFENCE(); __builtin_amdgcn_s_barrier(); SFENCE(); } while (0)

// ---------- kernel 0: routed-row lists ----------

__global__ void build_lists_kernel(const int* __restrict__ ridx,
                                   int* __restrict__ counts,
                                   int* __restrict__ lists) {
  int r = blockIdx.x * 256 + threadIdx.x;
  if (r >= MAXR) return;
  int e = ridx[r];
  int pos = atomicAdd(&counts[e], 1);
  lists[e * MAXR + pos] = r;
}

// ---------- kernel 0b: hidden f32 -> bf16 ----------

__global__ void cvt_kernel(const float* __restrict__ in, ushort* __restrict__ out) {
  int i = (blockIdx.x * 256 + threadIdx.x) * 8;
  float4 a = *(const float4*)(in + i);
  float4 b = *(const float4*)(in + i + 4);
  uint4 o;
  o.x = packbf2(a.x, a.y); o.y = packbf2(a.z, a.w);
  o.z = packbf2(b.x, b.y); o.w = packbf2(b.z, b.w);
  *(uint4*)(out + i) = o;
}

// ---------- kernel 1: gate_up GEMM + activation -> gated ----------
// 512 thr (8 waves: 4m x 2n), BM=320 x BN=128, flat grid e=bid&7 (XCD-affine).
// Counted-vmcnt pipeline. VMEM issue order per step (critical for vmcnt):
//   [oldest] A-DMA(ks+1) x5, B(ks+2) x3 [newest]
// so vmcnt(3) at step ks+1 == "A-DMA(ks+1) complete, B(ks+2) in flight".

__global__ __launch_bounds__(512, 4)
void gemm1_kernel(const char* __restrict__ wsb,
                  const int* __restrict__ guq,
                  const int* __restrict__ gus,
                  const float* __restrict__ gub,
                  const int* __restrict__ counts,
                  const int* __restrict__ lists,
                  ushort* __restrict__ gated) {
  const int e  = blockIdx.x & 7;
  const int xt = blockIdx.x >> 3;
  const int cnt = counts[e];
  const int mt = blockIdx.y;
  if (mt * BM >= cnt) return;
  const int gu0 = xt * 128;
  const int tid = threadIdx.x;

  __shared__ ushort lA[BM * 64];     // 40 KB
  __shared__ ushort lB[128 * 64];    // 16 KB
  __shared__ int rowid[BM];

  for (int i = tid; i < BM; i += 512) {
    int rl = mt * BM + i;
    rowid[i] = (rl < cnt) ? lists[e * MAXR + rl] : -1;
  }
  __syncthreads();

  const int ln = tid & 63, wv = tid >> 6;
  const int ln15 = ln & 15, kq = ln >> 4;
  const int wm = wv & 3, wn = wv >> 2;

  // A DMA: 5 calls/wave/step; linear LDS dest + pre-swizzled global source.
  uint aoff[5];
  #pragma unroll
  for (int j = 0; j < 5; ++j) {
    int slot = wv * 320 + j * 64 + ln;
    int row  = slot >> 3;
    int corig = (slot ^ row) & 7;
    int r = rowid[row];
    aoff[j] = (r >= 0) ? (HB_OFF + (uint)(r >> 1) * (HDIM * 2) + corig * 16)
                       : (ZROW_OFF + corig * 16);
  }
  // B staging: row = tid>>2 (128 rows), c2 = tid&3 -> 8 qbytes (2x dwordx4) + scale.
  const int brow = tid >> 2, c2 = tid & 3;
  const uint grow = (uint)(e * GU + gu0 + brow);
  const uint boff0 = grow * (QK1 * 4) + (uint)c2 * 32;
  const uint soff0 = grow * (SG1 * 4) + (uint)(c2 >> 1) * 4;
  const char* gq = (const char*)guq;
  const char* gs = (const char*)gus;

  f32x4 acc[5][4];
  #pragma unroll
  for (int m = 0; m < 5; ++m)
    #pragma unroll
    for (int n = 0; n < 4; ++n) acc[m][n] = (f32x4)0.f;

  int4 qa0, qa1, qb0, qb1;
  int  sa, sb;

  auto dmaA = [&](int ka) {
    #pragma unroll
    for (int j = 0; j < 5; ++j)
      __builtin_amdgcn_global_load_lds(
          (const __attribute__((address_space(1))) void*)(wsb + aoff[j] + (uint)ka * 128),
          (__attribute__((address_space(3))) void*)((char*)lA + (wv * 320 + j * 64) * 16),
          16, 0, 0);
  };
  auto loadB = [&](int kb, int4& q0, int4& q1, int& sv) {
    q0 = *(const int4*)(gq + boff0 + (uint)kb * 128);
    q1 = *(const int4*)(gq + boff0 + (uint)kb * 128 + 16);
    sv = *(const int*)(gs + soff0 + (uint)kb * 8);
  };

  // prologue: B(0) | A-DMA(0) | B(1)   (issue order matters for vmcnt)
  loadB(0, qa0, qa1, sa);
  SFENCE();
  dmaA(0);
  SFENCE();
  loadB(1, qb0, qb1, sb);
  SFENCE();

  auto step = [&](int ks, int4& q0, int4& q1, int& sv) {
    // decode B(ks) + ds_write (compiler auto-waits q regs via data dep)
    {
      uint P0 = (uint)q0.x | ((uint)q0.y << 8) | ((uint)q0.z << 16) | ((uint)q0.w << 24);
      uint P1 = (uint)q1.x | ((uint)q1.y << 8) | ((uint)q1.z << 16) | ((uint)q1.w << 24);
      uint sOff = ((uint)(sv - 127) << 7) & 0xFFFFu;
      uint sAdd2 = sOff | (sOff << 16);
      uint o0[4], o1[4];
      decode8(P0, sAdd2, o0);
      decode8(P1, sAdd2, o1);
      uint4 w0; w0.x = o0[0]; w0.y = o0[1]; w0.z = o0[2]; w0.w = o0[3];
      uint4 w1; w1.x = o1[0]; w1.y = o1[1]; w1.z = o1[2]; w1.w = o1[3];
      *(uint4*)&lB[ls(brow, 2 * c2)]     = w0;
      *(uint4*)&lB[ls(brow, 2 * c2 + 1)] = w1;
    }
    SFENCE();
    // A-DMA(ks) complete (oldest 5); only B(ks+1)'s 3 loads stay in flight.
    asm volatile("s_waitcnt vmcnt(3) lgkmcnt(0)" ::: "memory");
    SBAR();                                    // tile ks fully in LDS
    __builtin_amdgcn_s_setprio(1);
    #pragma unroll
    for (int kf = 0; kf < 2; ++kf) {
      const int cc = kf * 4 + kq;
      bf16x8 b0 = *(const bf16x8*)&lB[ls(wn * 64 +  0 + ln15, cc)];
      bf16x8 b1 = *(const bf16x8*)&lB[ls(wn * 64 + 16 + ln15, cc)];
      bf16x8 b2 = *(const bf16x8*)&lB[ls(wn * 64 + 32 + ln15, cc)];
      bf16x8 b3 = *(const bf16x8*)&lB[ls(wn * 64 + 48 + ln15, cc)];
      #pragma unroll
      for (int m = 0; m < 5; ++m) {
        bf16x8 af = *(const bf16x8*)&lA[ls(wm * 80 + m * 16 + ln15, cc)];
        acc[m][0] = __builtin_amdgcn_mfma_f32_16x16x32_bf16(af, b0, acc[m][0], 0, 0, 0);
        acc[m][1] = __builtin_amdgcn_mfma_f32_16x16x32_bf16(af, b1, acc[m][1], 0, 0, 0);
        acc[m][2] = __builtin_amdgcn_mfma_f32_16x16x32_bf16(af, b2, acc[m][2], 0, 0, 0);
        acc[m][3] = __builtin_amdgcn_mfma_f32_16x16x32_bf16(af, b3, acc[m][3], 0, 0, 0);
      }
    }
    __builtin_amdgcn_s_setprio(0);
    SBAR();                                    // all waves done reading tile ks
    // A-DMA(ks+1) into now-free lA, THEN B(ks+2): keeps B newest for vmcnt(3).
    dmaA((ks + 1 < NK) ? ks + 1 : NK - 1);
    SFENCE();
    {
      int kb = (ks + 2 < NK) ? ks + 2 : NK - 1;
      loadB(kb, q0, q1, sv);
    }
    SFENCE();
  };

  for (int ks = 0; ks < NK - 1; ks += 2) {
    step(ks,     qa0, qa1, sa);
    step(ks + 1, qb0, qb1, sb);
  }
  step(NK - 1, qa0, qa1, sa);
  asm volatile("s_waitcnt vmcnt(0)" ::: "memory");

  // epilogue: bias, pair g/u via shfl_xor(1) (gu parity == lane parity), glu
  float bias[4];
  #pragma unroll
  for (int n = 0; n < 4; ++n)
    bias[n] = gub[(size_t)e * GU + gu0 + wn * 64 + n * 16 + ln15];
  #pragma unroll
  for (int m = 0; m < 5; ++m) {
    #pragma unroll
    for (int rg = 0; rg < 4; ++rg) {
      int row = wm * 80 + m * 16 + kq * 4 + rg;
      int r = rowid[row];
      #pragma unroll
      for (int n = 0; n < 4; ++n) {
        float x = acc[m][n][rg] + bias[n];
        float y = __shfl_xor(x, 1);
        if (r >= 0 && !(ln & 1)) {
          float g = fminf(x, 7.f);
          float u = fminf(fmaxf(y, -7.f), 7.f);
          float glu = g / (1.f + __expf(-1.702f * g));
          float val = (u + 1.f) * glu;
          int gucol = gu0 + wn * 64 + n * 16 + ln15;
          gated[(size_t)r * IDIM + (gucol >> 1)] =
              __builtin_bit_cast(ushort, __float2bfloat16(val));
        }
      }
    }
  }
}

// ---------- kernel 1-fallback (ws too small): 256 thr, simple 2-barrier ----------

__global__ __launch_bounds__(256, 2)
void gemm1_fb(const float* __restrict__ hiddenF,
              const int* __restrict__ guq,
              const int* __restrict__ gus,
              const float* __restrict__ gub,
              const int* __restrict__ counts,
              const int* __restrict__ lists,
              ushort* __restrict__ gated) {
  const int e  = blockIdx.x & 7;
  const int xt = blockIdx.x >> 3;
  const int cnt = counts[e];
  const int mt = blockIdx.y;
  if (mt * BM >= cnt) return;
  const int gu0 = xt * 64;
  const int tid = threadIdx.x;

  __shared__ ushort lA[BM * 64];
  __shared__ ushort lB[64 * 64];
  __shared__ int rowid[BM];

  for (int i = tid; i < BM; i += 256) {
    int rl = mt * BM + i;
    rowid[i] = (rl < cnt) ? lists[e * MAXR + rl] : -1;
  }
  __syncthreads();

  const int ln = tid & 63, wv = tid >> 6;
  const int ln15 = ln & 15, kq = ln >> 4;
  const int arow = tid >> 3, ac = tid & 7;
  const int brow = tid >> 2, c2 = tid & 3;
  const uint grow = (uint)(e * GU + gu0 + brow);
  const uint boff0 = grow * (QK1 * 4) + (uint)c2 * 32;
  const uint soff0 = grow * (SG1 * 4) + (uint)(c2 >> 1) * 4;
  const char* gq = (const char*)guq;
  const char* gs = (const char*)gus;

  f32x4 acc[5][4];
  #pragma unroll
  for (int m = 0; m < 5; ++m)
    #pragma unroll
    for (int n = 0; n < 4; ++n) acc[m][n] = (f32x4)0.f;

  for (int ks = 0; ks < NK; ++ks) {
    #pragma unroll
    for (int j = 0; j < 10; ++j) {
      int row = arow + 32 * j;
      int r = rowid[row];
      uint4 o;
      if (r >= 0) {
        const float4* f = (const float4*)(hiddenF + (size_t)(r >> 1) * HDIM + ac * 8 + ks * 64);
        float4 f0 = f[0], f1 = f[1];
        o.x = packbf2(f0.x, f0.y); o.y = packbf2(f0.z, f0.w);
        o.z = packbf2(f1.x, f1.y); o.w = packbf2(f1.z, f1.w);
      } else { o.x = o.y = o.z = o.w = 0u; }
      *(uint4*)&lA[ls(row, ac)] = o;
    }
    {
      int4 b0 = *(const int4*)(gq + boff0 + (uint)ks * 128);
      int4 b1 = *(const int4*)(gq + boff0 + (uint)ks * 128 + 16);
      int  sv = *(const int*)(gs + soff0 + (uint)ks * 8);
      uint P0 = (uint)b0.x | ((uint)b0.y << 8) | ((uint)b0.z << 16) | ((uint)b0.w << 24);
      uint P1 = (uint)b1.x | ((uint)b1.y << 8) | ((uint)b1.z << 16) | ((uint)b1.w << 24);
      uint sOff = ((uint)(sv - 127) << 7) & 0xFFFFu;
      uint sAdd2 = sOff | (sOff << 16);
      uint o0[4], o1[4];
      decode8(P0, sAdd2, o0);
      decode8(P1, sAdd2, o1);
      uint4 w0; w0.x = o0[0]; w0.y = o0[1]; w0.z = o0[2]; w0.w = o0[3];
      uint4 w1; w1.x = o1[0]; w1.y = o1[1]; w1.z = o1[2]; w1.w = o1[3];
      *(uint4*)&lB[ls(brow, 2 * c2)]     = w0;
      *(uint4*)&lB[ls(brow, 2 * c2 + 1)] = w1;
    }
    __syncthreads();
    #pragma unroll
    for (int kf = 0; kf < 2; ++kf) {
      const int cc = kf * 4 + kq;
      bf16x8 bfr[4];
      #pragma unroll
      for (int n = 0; n < 4; ++n)
        bfr[n] = *(const bf16x8*)&lB[ls(n * 16 + ln15, cc)];
      #pragma unroll
      for (int m = 0; m < 5; ++m) {
        bf16x8 af = *(const bf16x8*)&lA[ls(wv * 80 + m * 16 + ln15, cc)];
        #pragma unroll
        for (int n = 0; n < 4; ++n)
          acc[m][n] = __builtin_amdgcn_mfma_f32_16x16x32_bf16(af, bfr[n], acc[m][n], 0, 0, 0);
      }
    }
    __syncthreads();
  }

  float bias[4];
  #pragma unroll
  for (int n = 0; n < 4; ++n)
    bias[n] = gub[(size_t)e * GU + gu0 + n * 16 + ln15];
  #pragma unroll
  for (int m = 0; m < 5; ++m) {
    #pragma unroll
    for (int rg = 0; rg < 4; ++rg) {
      int row = wv * 80 + m * 16 + kq * 4 + rg;
      int r = rowid[row];
      #pragma unroll
      for (int n = 0; n < 4; ++n) {
        float x = acc[m][n][rg] + bias[n];
        float y = __shfl_xor(x, 1);
        if (r >= 0 && !(ln & 1)) {
          float g = fminf(x, 7.f);
          float u = fminf(fmaxf(y, -7.f), 7.f);
          float glu = g / (1.f + __expf(-1.702f * g));
          float val = (u + 1.f) * glu;
          int gucol = gu0 + n * 16 + ln15;
          gated[(size_t)r * IDIM + (gucol >> 1)] =
              __builtin_bit_cast(ushort, __float2bfloat16(val));
        }
      }
    }
  }
}

// ---------- kernel 2: down GEMM + routed scatter-add ----------
// 512 thr (8 waves: 4m x 2n), BM=320 x BN=64, same counted-vmcnt pipeline.

__global__ __launch_bounds__(512, 4)
void gemm2_kernel(const char* __restrict__ wsb, uint gatedOff,
                  const int* __restrict__ dq,
                  const int* __restrict__ dsc,
                  const float* __restrict__ dpb,
                  const float* __restrict__ routing,
                  const int* __restrict__ counts,
                  const int* __restrict__ lists,
                  float* __restrict__ outp) {
  const int e  = blockIdx.x & 7;
  const int ht = blockIdx.x >> 3;
  const int cnt = counts[e];
  const int mt = blockIdx.y;
  if (mt * BM >= cnt) return;
  const int h0 = ht * 64;
  const int tid = threadIdx.x;

  __shared__ ushort lA[BM * 64];
  __shared__ ushort lB[64 * 64];
  __shared__ int rowid[BM];

  for (int i = tid; i < BM; i += 512) {
    int rl = mt * BM + i;
    rowid[i] = (rl < cnt) ? lists[e * MAXR + rl] : -1;
  }
  __syncthreads();

  const int ln = tid & 63, wv = tid >> 6;
  const int ln15 = ln & 15, kq = ln >> 4;
  const int wm = wv & 3, wn = wv >> 2;

  uint aoff[5];
  #pragma unroll
  for (int j = 0; j < 5; ++j) {
    int slot = wv * 320 + j * 64 + ln;
    int row  = slot >> 3;
    int corig = (slot ^ row) & 7;
    int r = rowid[row];
    aoff[j] = (r >= 0) ? (gatedOff + (uint)r * (IDIM * 2) + corig * 16)
                       : (ZROW_OFF + corig * 16);
  }
  // B staging: row = tid>>3 (64 rows), c3 = tid&7 -> 4 qbytes (dwordx4) + scale.
  const int brow = tid >> 3, c3 = tid & 7;
  const uint hrow = (uint)(e * HDIM + h0 + brow);
  const uint boff0 = hrow * (QK2 * 4) + (uint)c3 * 16;
  const uint soff0 = hrow * (SG2 * 4) + (uint)(c3 >> 2) * 4;
  const char* gq = (const char*)dq;
  const char* gs = (const char*)dsc;

  f32x4 acc[5][2];
  #pragma unroll
  for (int m = 0; m < 5; ++m) { acc[m][0] = (f32x4)0.f; acc[m][1] = (f32x4)0.f; }

  int4 qa; int sa;
  int4 qb; int sb;

  auto dmaA = [&](int ka) {
    #pragma unroll
    for (int j = 0; j < 5; ++j)
      __builtin_amdgcn_global_load_lds(
          (const __attribute__((address_space(1))) void*)(wsb + aoff[j] + (uint)ka * 128),
          (__attribute__((address_space(3))) void*)((char*)lA + (wv * 320 + j * 64) * 16),
          16, 0, 0);
  };
  auto loadB = [&](int kb, int4& q0, int& sv) {
    q0 = *(const int4*)(gq + boff0 + (uint)kb * 128);
    sv = *(const int*)(gs + soff0 + (uint)kb * 8);
  };

  loadB(0, qa, sa);
  SFENCE();
  dmaA(0);
  SFENCE();
  loadB(1, qb, sb);
  SFENCE();

  auto step = [&](int ks, int4& q0, int& sv) {
    {
      uint P = (uint)q0.x | ((uint)q0.y << 8) | ((uint)q0.z << 16) | ((uint)q0.w << 24);
      uint sOff = ((uint)(sv - 127) << 7) & 0xFFFFu;
      uint sAdd2 = sOff | (sOff << 16);
      uint o[4];
      decode8(P, sAdd2, o);
      uint4 w; w.x = o[0]; w.y = o[1]; w.z = o[2]; w.w = o[3];
      *(uint4*)&lB[ls(brow, c3)] = w;
    }
    SFENCE();
    asm volatile("s_waitcnt vmcnt(2) lgkmcnt(0)" ::: "memory");
    SBAR();
    __builtin_amdgcn_s_setprio(1);
    #pragma unroll
    for (int kf = 0; kf < 2; ++kf) {
      const int cc = kf * 4 + kq;
      bf16x8 b0 = *(const bf16x8*)&lB[ls(wn * 32 +  0 + ln15, cc)];
      bf16x8 b1 = *(const bf16x8*)&lB[ls(wn * 32 + 16 + ln15, cc)];
      #pragma unroll
      for (int m = 0; m < 5; ++m) {
        bf16x8 af = *(const bf16x8*)&lA[ls(wm * 80 + m * 16 + ln15, cc)];
        acc[m][0] = __builtin_amdgcn_mfma_f32_16x16x32_bf16(af, b0, acc[m][0], 0, 0, 0);
        acc[m][1] = __builtin_amdgcn_mfma_f32_16x16x32_bf16(af, b1, acc[m][1], 0, 0, 0);
      }
    }
    __builtin_amdgcn_s_setprio(0);
    SBAR();
    dmaA((ks + 1 < NK) ? ks + 1 : NK - 1);
    SFENCE();
    loadB((ks + 2 < NK) ? ks + 2 : NK - 1, q0, sv);
    SFENCE();
  };

  for (int ks = 0; ks < NK - 1; ks += 2) {
    step(ks,     qa, sa);
    step(ks + 1, qb, sb);
  }
  step(NK - 1, qa, sa);
  asm volatile("s_waitcnt vmcnt(0)" ::: "memory");

  float bias[2];
  #pragma unroll
  for (int n = 0; n < 2; ++n)
    bias[n] = dpb[(size_t)e * HDIM + h0 + wn * 32 + n * 16 + ln15];
  #pragma unroll
  for (int m = 0; m < 5; ++m) {
    #pragma unroll
    for (int rg = 0; rg < 4; ++rg) {
      int row = wm * 80 + m * 16 + kq * 4 + rg;
      int r = rowid[row];
      if (r < 0) continue;
      float wgt = routing[r];
      #pragma unroll
      for (int n = 0; n < 2; ++n) {
        int hcol = h0 + wn * 32 + n * 16 + ln15;
        atomicAdd(outp + (size_t)(r >> 1) * HDIM + hcol,
                  wgt * (acc[m][n][rg] + bias[n]));
      }
    }
  }
}

// ---------- launch ----------

extern "C" void kernel_launch(void* const* d_in, const int* in_sizes, int n_in,
                              void* d_out, int out_size, void* d_ws, size_t ws_size,
                              hipStream_t stream) {
  const float* hidden  = (const float*)d_in[0];
  const float* routing = (const float*)d_in[1];
  const float* gub     = (const float*)d_in[2];
  const float* dpb     = (const float*)d_in[3];
  const int*   ridx    = (const int*)d_in[4];
  const int*   guq     = (const int*)d_in[5];
  const int*   gus     = (const int*)d_in[6];
  const int*   dq      = (const int*)d_in[7];
  const int*   dsc     = (const int*)d_in[8];
  float* outp = (float*)d_out;

  char* ws = (char*)d_ws;
  int* counts = (int*)ws;
  int* lists  = (int*)(ws + 256);
  const bool pre = (ws_size >= WS_NEED);
  const uint gatedOff = pre ? GATED_OFF_PRE : HB_OFF;
  ushort* hb    = (ushort*)(ws + HB_OFF);
  ushort* gated = (ushort*)(ws + gatedOff);

  hipMemsetAsync(counts, 0, 256, stream);
  hipMemsetAsync(ws + ZROW_OFF, 0, 8192, stream);
  hipMemsetAsync(d_out, 0, (size_t)out_size * sizeof(float), stream);

  build_lists_kernel<<<MAXR / 256, 256, 0, stream>>>(ridx, counts, lists);
  if (pre)
    cvt_kernel<<<(T_TOK * HDIM / 8) / 256, 256, 0, stream>>>(hidden, hb);

  const int mtiles = (MAXR + BM - 1) / BM;
  if (pre) {
    dim3 grid1((GU / 128) * NEXP, mtiles);
    gemm1_kernel<<<grid1, 512, 0, stream>>>(ws, guq, gus, gub, counts, lists, gated);
  } else {
    dim3 grid1f((GU / 64) * NEXP, mtiles);
    gemm1_fb<<<grid1f, 256, 0, stream>>>(hidden, guq, gus, gub, counts, lists, gated);
  }

  dim3 grid2((HDIM / 64) * NEXP, mtiles);
  gemm2_kernel<<<grid2, 512, 0, stream>>>(ws, gatedOff, dq, dsc, dpb, routing,
                                          counts, lists, outp);
}

// Round 7
// 342.620 us; speedup vs baseline: 2.0329x; 2.0329x over previous
//
#include <hip/hip_runtime.h>
#include <hip/hip_bf16.h>

typedef unsigned int uint;
typedef unsigned short ushort;
typedef __bf16 bf16x8 __attribute__((ext_vector_type(8)));
typedef float f32x4 __attribute__((ext_vector_type(4)));
typedef unsigned short u16x2 __attribute__((ext_vector_type(2)));

#define T_TOK 1024
#define HDIM 2880
#define IDIM 2880
#define NEXP 8
#define GU 5760
#define QK1 1440
#define SG1 90
#define QK2 1440
#define SG2 90
#define MAXR 2048
#define NK 45
#define BM 320

#define ZROW_OFF 98304u
#define HB_OFF 131072u
#define GATED_OFF_PRE 6029312u              // HB_OFF + 1024*2880*2
#define WS_NEED (GATED_OFF_PRE + (size_t)MAXR * IDIM * 2)

// T2 swizzle (proven conflict-free in R3/R6: SQ_LDS_BANK_CONFLICT = 0).
static __device__ __forceinline__ int ls(int row, int c) {
  return (row << 6) + (((c ^ row) & 7) << 3);
}

static __device__ __forceinline__ uint pkadd16(uint a, uint b) {
  u16x2 x = __builtin_bit_cast(u16x2, a);
  u16x2 y = __builtin_bit_cast(u16x2, b);
  u16x2 r = x + y;
  return __builtin_bit_cast(uint, r);
}

// Decode 4 fp4-pair bytes (one byte per int32, packed into P) into 4 dwords of
// 2×bf16 (low nibble = even k first), E8M0 scale fused as exponent add (exact).
static __device__ __forceinline__ void decode8(uint P, uint sAdd2, uint out[4]) {
  uint L  = P & 0x0F0F0F0Fu;
  uint Hh = (P >> 4) & 0x0F0F0F0Fu;
  uint Lm = L & 0x07070707u,  Hm = Hh & 0x07070707u;
  uint Lsg = (L & 0x08080808u) << 4, Hsg = (Hh & 0x08080808u) << 4;
  uint hiL = __builtin_amdgcn_perm(0x40404040u, 0x3F3F3F00u, Lm) | Lsg;
  uint hiH = __builtin_amdgcn_perm(0x40404040u, 0x3F3F3F00u, Hm) | Hsg;
  uint loL = __builtin_amdgcn_perm(0xC0804000u, 0xC0800000u, Lm);
  uint loH = __builtin_amdgcn_perm(0xC0804000u, 0xC0800000u, Hm);
  uint mL  = __builtin_amdgcn_perm(0xFFFFFFFFu, 0xFFFFFF00u, Lm);
  uint mH  = __builtin_amdgcn_perm(0xFFFFFFFFu, 0xFFFFFF00u, Hm);
  uint pL01 = __builtin_amdgcn_perm(hiL, loL, 0x05010400u);
  uint pL23 = __builtin_amdgcn_perm(hiL, loL, 0x07030602u);
  uint pH01 = __builtin_amdgcn_perm(hiH, loH, 0x05010400u);
  uint pH23 = __builtin_amdgcn_perm(hiH, loH, 0x07030602u);
  uint aL01 = pkadd16(pL01, sAdd2 & __builtin_amdgcn_perm(mL, mL, 0x01010000u));
  uint aL23 = pkadd16(pL23, sAdd2 & __builtin_amdgcn_perm(mL, mL, 0x03030202u));
  uint aH01 = pkadd16(pH01, sAdd2 & __builtin_amdgcn_perm(mH, mH, 0x01010000u));
  uint aH23 = pkadd16(pH23, sAdd2 & __builtin_amdgcn_perm(mH, mH, 0x03030202u));
  out[0] = __builtin_amdgcn_perm(aH01, aL01, 0x05040100u);
  out[1] = __builtin_amdgcn_perm(aH01, aL01, 0x07060302u);
  out[2] = __builtin_amdgcn_perm(aH23, aL23, 0x05040100u);
  out[3] = __builtin_amdgcn_perm(aH23, aL23, 0x07060302u);
}

static __device__ __forceinline__ uint packbf2(float a, float b) {
  ushort ua = __builtin_bit_cast(ushort, __float2bfloat16(a));
  ushort ub = __builtin_bit_cast(ushort, __float2bfloat16(b));
  return (uint)ua | ((uint)ub << 16);
}

#define SFENCE() __builtin_amdgcn_sched_barrier(0)
#define SBAR() do { SFENCE(); __builtin_amdgcn_s_barrier(); SFENCE(); } while (0)

// ---------- kernel 0: routed-row lists ----------

__global__ void build_lists_kernel(const int* __restrict__ ridx,
                                   int* __restrict__ counts,
                                   int* __restrict__ lists) {
  int r = blockIdx.x * 256 + threadIdx.x;
  if (r >= MAXR) return;
  int e = ridx[r];
  int pos = atomicAdd(&counts[e], 1);
  lists[e * MAXR + pos] = r;
}

// ---------- kernel 0b: hidden f32 -> bf16 ----------

__global__ void cvt_kernel(const float* __restrict__ in, ushort* __restrict__ out) {
  int i = (blockIdx.x * 256 + threadIdx.x) * 8;
  float4 a = *(const float4*)(in + i);
  float4 b = *(const float4*)(in + i + 4);
  uint4 o;
  o.x = packbf2(a.x, a.y); o.y = packbf2(a.z, a.w);
  o.z = packbf2(b.x, b.y); o.w = packbf2(b.z, b.w);
  *(uint4*)(out + i) = o;
}

// ---------- kernel 1: gate_up GEMM + activation -> gated ----------
// 512 thr (8 waves: 4m x 2n), BM=320 x BN=128, flat grid e=bid&7 (XCD-affine).
// Counted-vmcnt pipeline; VMEM issue order per step (critical for vmcnt):
//   [oldest] A-DMA(ks+1) x5, B(ks+2) x3 [newest]
// launch_bounds (512,2): 256-reg budget -> acc[5][4] + B regs fit, NO spill
// (R6 lesson: (512,4) capped at 128 regs -> 627 MB scratch traffic).

__global__ __launch_bounds__(512, 2)
void gemm1_kernel(const char* __restrict__ wsb,
                  const int* __restrict__ guq,
                  const int* __restrict__ gus,
                  const float* __restrict__ gub,
                  const int* __restrict__ counts,
                  const int* __restrict__ lists,
                  ushort* __restrict__ gated) {
  const int e  = blockIdx.x & 7;
  const int xt = blockIdx.x >> 3;
  const int cnt = counts[e];
  const int mt = blockIdx.y;
  if (mt * BM >= cnt) return;
  const int gu0 = xt * 128;
  const int tid = threadIdx.x;

  __shared__ ushort lA[BM * 64];     // 40 KB
  __shared__ ushort lB[128 * 64];    // 16 KB
  __shared__ int rowid[BM];

  for (int i = tid; i < BM; i += 512) {
    int rl = mt * BM + i;
    rowid[i] = (rl < cnt) ? lists[e * MAXR + rl] : -1;
  }
  __syncthreads();

  const int ln = tid & 63, wv = tid >> 6;
  const int ln15 = ln & 15, kq = ln >> 4;
  const int wm = wv & 3, wn = wv >> 2;

  // A DMA: 5 calls/wave/step; linear LDS dest + pre-swizzled global source.
  uint aoff[5];
  #pragma unroll
  for (int j = 0; j < 5; ++j) {
    int slot = wv * 320 + j * 64 + ln;
    int row  = slot >> 3;
    int corig = (slot ^ row) & 7;
    int r = rowid[row];
    aoff[j] = (r >= 0) ? (HB_OFF + (uint)(r >> 1) * (HDIM * 2) + corig * 16)
                       : (ZROW_OFF + corig * 16);
  }
  // B staging: row = tid>>2 (128 rows), c2 = tid&3 -> 8 qbytes (2x dwordx4) + scale.
  const int brow = tid >> 2, c2 = tid & 3;
  const uint grow = (uint)(e * GU + gu0 + brow);
  const uint boff0 = grow * (QK1 * 4) + (uint)c2 * 32;
  const uint soff0 = grow * (SG1 * 4) + (uint)(c2 >> 1) * 4;
  const char* gq = (const char*)guq;
  const char* gs = (const char*)gus;

  f32x4 acc[5][4];
  #pragma unroll
  for (int m = 0; m < 5; ++m)
    #pragma unroll
    for (int n = 0; n < 4; ++n) acc[m][n] = (f32x4)0.f;

  int4 qa0, qa1, qb0, qb1;
  int  sa, sb;

  auto dmaA = [&](int ka) {
    #pragma unroll
    for (int j = 0; j < 5; ++j)
      __builtin_amdgcn_global_load_lds(
          (const __attribute__((address_space(1))) void*)(wsb + aoff[j] + (uint)ka * 128),
          (__attribute__((address_space(3))) void*)((char*)lA + (wv * 320 + j * 64) * 16),
          16, 0, 0);
  };
  auto loadB = [&](int kb, int4& q0, int4& q1, int& sv) {
    q0 = *(const int4*)(gq + boff0 + (uint)kb * 128);
    q1 = *(const int4*)(gq + boff0 + (uint)kb * 128 + 16);
    sv = *(const int*)(gs + soff0 + (uint)kb * 8);
  };

  // prologue: B(0) | A-DMA(0) | B(1)   (issue order matters for vmcnt)
  loadB(0, qa0, qa1, sa);
  SFENCE();
  dmaA(0);
  SFENCE();
  loadB(1, qb0, qb1, sb);
  SFENCE();

  auto step = [&](int ks, int4& q0, int4& q1, int& sv) {
    // decode B(ks) + ds_write (compiler auto-waits q regs via data dep)
    {
      uint P0 = (uint)q0.x | ((uint)q0.y << 8) | ((uint)q0.z << 16) | ((uint)q0.w << 24);
      uint P1 = (uint)q1.x | ((uint)q1.y << 8) | ((uint)q1.z << 16) | ((uint)q1.w << 24);
      uint sOff = ((uint)(sv - 127) << 7) & 0xFFFFu;
      uint sAdd2 = sOff | (sOff << 16);
      uint o0[4], o1[4];
      decode8(P0, sAdd2, o0);
      decode8(P1, sAdd2, o1);
      uint4 w0; w0.x = o0[0]; w0.y = o0[1]; w0.z = o0[2]; w0.w = o0[3];
      uint4 w1; w1.x = o1[0]; w1.y = o1[1]; w1.z = o1[2]; w1.w = o1[3];
      *(uint4*)&lB[ls(brow, 2 * c2)]     = w0;
      *(uint4*)&lB[ls(brow, 2 * c2 + 1)] = w1;
    }
    SFENCE();
    // A-DMA(ks) complete (oldest 5); only B(ks+1)'s 3 loads stay in flight.
    asm volatile("s_waitcnt vmcnt(3) lgkmcnt(0)" ::: "memory");
    SBAR();                                    // tile ks fully in LDS
    __builtin_amdgcn_s_setprio(1);
    #pragma unroll
    for (int kf = 0; kf < 2; ++kf) {
      const int cc = kf * 4 + kq;
      bf16x8 b0 = *(const bf16x8*)&lB[ls(wn * 64 +  0 + ln15, cc)];
      bf16x8 b1 = *(const bf16x8*)&lB[ls(wn * 64 + 16 + ln15, cc)];
      bf16x8 b2 = *(const bf16x8*)&lB[ls(wn * 64 + 32 + ln15, cc)];
      bf16x8 b3 = *(const bf16x8*)&lB[ls(wn * 64 + 48 + ln15, cc)];
      #pragma unroll
      for (int m = 0; m < 5; ++m) {
        bf16x8 af = *(const bf16x8*)&lA[ls(wm * 80 + m * 16 + ln15, cc)];
        acc[m][0] = __builtin_amdgcn_mfma_f32_16x16x32_bf16(af, b0, acc[m][0], 0, 0, 0);
        acc[m][1] = __builtin_amdgcn_mfma_f32_16x16x32_bf16(af, b1, acc[m][1], 0, 0, 0);
        acc[m][2] = __builtin_amdgcn_mfma_f32_16x16x32_bf16(af, b2, acc[m][2], 0, 0, 0);
        acc[m][3] = __builtin_amdgcn_mfma_f32_16x16x32_bf16(af, b3, acc[m][3], 0, 0, 0);
      }
    }
    __builtin_amdgcn_s_setprio(0);
    SBAR();                                    // all waves done reading tile ks
    // A-DMA(ks+1) into now-free lA, THEN B(ks+2): keeps B newest for vmcnt(3).
    dmaA((ks + 1 < NK) ? ks + 1 : NK - 1);
    SFENCE();
    {
      int kb = (ks + 2 < NK) ? ks + 2 : NK - 1;
      loadB(kb, q0, q1, sv);
    }
    SFENCE();
  };

  for (int ks = 0; ks < NK - 1; ks += 2) {
    step(ks,     qa0, qa1, sa);
    step(ks + 1, qb0, qb1, sb);
  }
  step(NK - 1, qa0, qa1, sa);
  asm volatile("s_waitcnt vmcnt(0)" ::: "memory");

  // epilogue: bias, pair g/u via shfl_xor(1) (gu parity == lane parity), glu
  float bias[4];
  #pragma unroll
  for (int n = 0; n < 4; ++n)
    bias[n] = gub[(size_t)e * GU + gu0 + wn * 64 + n * 16 + ln15];
  #pragma unroll
  for (int m = 0; m < 5; ++m) {
    #pragma unroll
    for (int rg = 0; rg < 4; ++rg) {
      int row = wm * 80 + m * 16 + kq * 4 + rg;
      int r = rowid[row];
      #pragma unroll
      for (int n = 0; n < 4; ++n) {
        float x = acc[m][n][rg] + bias[n];
        float y = __shfl_xor(x, 1);
        if (r >= 0 && !(ln & 1)) {
          float g = fminf(x, 7.f);
          float u = fminf(fmaxf(y, -7.f), 7.f);
          float glu = g / (1.f + __expf(-1.702f * g));
          float val = (u + 1.f) * glu;
          int gucol = gu0 + wn * 64 + n * 16 + ln15;
          gated[(size_t)r * IDIM + (gucol >> 1)] =
              __builtin_bit_cast(ushort, __float2bfloat16(val));
        }
      }
    }
  }
}

// ---------- kernel 1-fallback (ws too small): 256 thr, simple 2-barrier ----------

__global__ __launch_bounds__(256, 2)
void gemm1_fb(const float* __restrict__ hiddenF,
              const int* __restrict__ guq,
              const int* __restrict__ gus,
              const float* __restrict__ gub,
              const int* __restrict__ counts,
              const int* __restrict__ lists,
              ushort* __restrict__ gated) {
  const int e  = blockIdx.x & 7;
  const int xt = blockIdx.x >> 3;
  const int cnt = counts[e];
  const int mt = blockIdx.y;
  if (mt * BM >= cnt) return;
  const int gu0 = xt * 64;
  const int tid = threadIdx.x;

  __shared__ ushort lA[BM * 64];
  __shared__ ushort lB[64 * 64];
  __shared__ int rowid[BM];

  for (int i = tid; i < BM; i += 256) {
    int rl = mt * BM + i;
    rowid[i] = (rl < cnt) ? lists[e * MAXR + rl] : -1;
  }
  __syncthreads();

  const int ln = tid & 63, wv = tid >> 6;
  const int ln15 = ln & 15, kq = ln >> 4;
  const int arow = tid >> 3, ac = tid & 7;
  const int brow = tid >> 2, c2 = tid & 3;
  const uint grow = (uint)(e * GU + gu0 + brow);
  const uint boff0 = grow * (QK1 * 4) + (uint)c2 * 32;
  const uint soff0 = grow * (SG1 * 4) + (uint)(c2 >> 1) * 4;
  const char* gq = (const char*)guq;
  const char* gs = (const char*)gus;

  f32x4 acc[5][4];
  #pragma unroll
  for (int m = 0; m < 5; ++m)
    #pragma unroll
    for (int n = 0; n < 4; ++n) acc[m][n] = (f32x4)0.f;

  for (int ks = 0; ks < NK; ++ks) {
    #pragma unroll
    for (int j = 0; j < 10; ++j) {
      int row = arow + 32 * j;
      int r = rowid[row];
      uint4 o;
      if (r >= 0) {
        const float4* f = (const float4*)(hiddenF + (size_t)(r >> 1) * HDIM + ac * 8 + ks * 64);
        float4 f0 = f[0], f1 = f[1];
        o.x = packbf2(f0.x, f0.y); o.y = packbf2(f0.z, f0.w);
        o.z = packbf2(f1.x, f1.y); o.w = packbf2(f1.z, f1.w);
      } else { o.x = o.y = o.z = o.w = 0u; }
      *(uint4*)&lA[ls(row, ac)] = o;
    }
    {
      int4 b0 = *(const int4*)(gq + boff0 + (uint)ks * 128);
      int4 b1 = *(const int4*)(gq + boff0 + (uint)ks * 128 + 16);
      int  sv = *(const int*)(gs + soff0 + (uint)ks * 8);
      uint P0 = (uint)b0.x | ((uint)b0.y << 8) | ((uint)b0.z << 16) | ((uint)b0.w << 24);
      uint P1 = (uint)b1.x | ((uint)b1.y << 8) | ((uint)b1.z << 16) | ((uint)b1.w << 24);
      uint sOff = ((uint)(sv - 127) << 7) & 0xFFFFu;
      uint sAdd2 = sOff | (sOff << 16);
      uint o0[4], o1[4];
      decode8(P0, sAdd2, o0);
      decode8(P1, sAdd2, o1);
      uint4 w0; w0.x = o0[0]; w0.y = o0[1]; w0.z = o0[2]; w0.w = o0[3];
      uint4 w1; w1.x = o1[0]; w1.y = o1[1]; w1.z = o1[2]; w1.w = o1[3];
      *(uint4*)&lB[ls(brow, 2 * c2)]     = w0;
      *(uint4*)&lB[ls(brow, 2 * c2 + 1)] = w1;
    }
    __syncthreads();
    #pragma unroll
    for (int kf = 0; kf < 2; ++kf) {
      const int cc = kf * 4 + kq;
      bf16x8 bfr[4];
      #pragma unroll
      for (int n = 0; n < 4; ++n)
        bfr[n] = *(const bf16x8*)&lB[ls(n * 16 + ln15, cc)];
      #pragma unroll
      for (int m = 0; m < 5; ++m) {
        bf16x8 af = *(const bf16x8*)&lA[ls(wv * 80 + m * 16 + ln15, cc)];
        #pragma unroll
        for (int n = 0; n < 4; ++n)
          acc[m][n] = __builtin_amdgcn_mfma_f32_16x16x32_bf16(af, bfr[n], acc[m][n], 0, 0, 0);
      }
    }
    __syncthreads();
  }

  float bias[4];
  #pragma unroll
  for (int n = 0; n < 4; ++n)
    bias[n] = gub[(size_t)e * GU + gu0 + n * 16 + ln15];
  #pragma unroll
  for (int m = 0; m < 5; ++m) {
    #pragma unroll
    for (int rg = 0; rg < 4; ++rg) {
      int row = wv * 80 + m * 16 + kq * 4 + rg;
      int r = rowid[row];
      #pragma unroll
      for (int n = 0; n < 4; ++n) {
        float x = acc[m][n][rg] + bias[n];
        float y = __shfl_xor(x, 1);
        if (r >= 0 && !(ln & 1)) {
          float g = fminf(x, 7.f);
          float u = fminf(fmaxf(y, -7.f), 7.f);
          float glu = g / (1.f + __expf(-1.702f * g));
          float val = (u + 1.f) * glu;
          int gucol = gu0 + n * 16 + ln15;
          gated[(size_t)r * IDIM + (gucol >> 1)] =
              __builtin_bit_cast(ushort, __float2bfloat16(val));
        }
      }
    }
  }
}

// ---------- kernel 2: down GEMM + routed scatter-add ----------
// 512 thr (8 waves: 4m x 2n), BM=320 x BN=64, same counted-vmcnt pipeline.

__global__ __launch_bounds__(512, 2)
void gemm2_kernel(const char* __restrict__ wsb, uint gatedOff,
                  const int* __restrict__ dq,
                  const int* __restrict__ dsc,
                  const float* __restrict__ dpb,
                  const float* __restrict__ routing,
                  const int* __restrict__ counts,
                  const int* __restrict__ lists,
                  float* __restrict__ outp) {
  const int e  = blockIdx.x & 7;
  const int ht = blockIdx.x >> 3;
  const int cnt = counts[e];
  const int mt = blockIdx.y;
  if (mt * BM >= cnt) return;
  const int h0 = ht * 64;
  const int tid = threadIdx.x;

  __shared__ ushort lA[BM * 64];
  __shared__ ushort lB[64 * 64];
  __shared__ int rowid[BM];

  for (int i = tid; i < BM; i += 512) {
    int rl = mt * BM + i;
    rowid[i] = (rl < cnt) ? lists[e * MAXR + rl] : -1;
  }
  __syncthreads();

  const int ln = tid & 63, wv = tid >> 6;
  const int ln15 = ln & 15, kq = ln >> 4;
  const int wm = wv & 3, wn = wv >> 2;

  uint aoff[5];
  #pragma unroll
  for (int j = 0; j < 5; ++j) {
    int slot = wv * 320 + j * 64 + ln;
    int row  = slot >> 3;
    int corig = (slot ^ row) & 7;
    int r = rowid[row];
    aoff[j] = (r >= 0) ? (gatedOff + (uint)r * (IDIM * 2) + corig * 16)
                       : (ZROW_OFF + corig * 16);
  }
  // B staging: row = tid>>3 (64 rows), c3 = tid&7 -> 4 qbytes (dwordx4) + scale.
  const int brow = tid >> 3, c3 = tid & 7;
  const uint hrow = (uint)(e * HDIM + h0 + brow);
  const uint boff0 = hrow * (QK2 * 4) + (uint)c3 * 16;
  const uint soff0 = hrow * (SG2 * 4) + (uint)(c3 >> 2) * 4;
  const char* gq = (const char*)dq;
  const char* gs = (const char*)dsc;

  f32x4 acc[5][2];
  #pragma unroll
  for (int m = 0; m < 5; ++m) { acc[m][0] = (f32x4)0.f; acc[m][1] = (f32x4)0.f; }

  int4 qa; int sa;
  int4 qb; int sb;

  auto dmaA = [&](int ka) {
    #pragma unroll
    for (int j = 0; j < 5; ++j)
      __builtin_amdgcn_global_load_lds(
          (const __attribute__((address_space(1))) void*)(wsb + aoff[j] + (uint)ka * 128),
          (__attribute__((address_space(3))) void*)((char*)lA + (wv * 320 + j * 64) * 16),
          16, 0, 0);
  };
  auto loadB = [&](int kb, int4& q0, int& sv) {
    q0 = *(const int4*)(gq + boff0 + (uint)kb * 128);
    sv = *(const int*)(gs + soff0 + (uint)kb * 8);
  };

  loadB(0, qa, sa);
  SFENCE();
  dmaA(0);
  SFENCE();
  loadB(1, qb, sb);
  SFENCE();

  auto step = [&](int ks, int4& q0, int& sv) {
    {
      uint P = (uint)q0.x | ((uint)q0.y << 8) | ((uint)q0.z << 16) | ((uint)q0.w << 24);
      uint sOff = ((uint)(sv - 127) << 7) & 0xFFFFu;
      uint sAdd2 = sOff | (sOff << 16);
      uint o[4];
      decode8(P, sAdd2, o);
      uint4 w; w.x = o[0]; w.y = o[1]; w.z = o[2]; w.w = o[3];
      *(uint4*)&lB[ls(brow, c3)] = w;
    }
    SFENCE();
    asm volatile("s_waitcnt vmcnt(2) lgkmcnt(0)" ::: "memory");
    SBAR();
    __builtin_amdgcn_s_setprio(1);
    #pragma unroll
    for (int kf = 0; kf < 2; ++kf) {
      const int cc = kf * 4 + kq;
      bf16x8 b0 = *(const bf16x8*)&lB[ls(wn * 32 +  0 + ln15, cc)];
      bf16x8 b1 = *(const bf16x8*)&lB[ls(wn * 32 + 16 + ln15, cc)];
      #pragma unroll
      for (int m = 0; m < 5; ++m) {
        bf16x8 af = *(const bf16x8*)&lA[ls(wm * 80 + m * 16 + ln15, cc)];
        acc[m][0] = __builtin_amdgcn_mfma_f32_16x16x32_bf16(af, b0, acc[m][0], 0, 0, 0);
        acc[m][1] = __builtin_amdgcn_mfma_f32_16x16x32_bf16(af, b1, acc[m][1], 0, 0, 0);
      }
    }
    __builtin_amdgcn_s_setprio(0);
    SBAR();
    dmaA((ks + 1 < NK) ? ks + 1 : NK - 1);
    SFENCE();
    loadB((ks + 2 < NK) ? ks + 2 : NK - 1, q0, sv);
    SFENCE();
  };

  for (int ks = 0; ks < NK - 1; ks += 2) {
    step(ks,     qa, sa);
    step(ks + 1, qb, sb);
  }
  step(NK - 1, qa, sa);
  asm volatile("s_waitcnt vmcnt(0)" ::: "memory");

  float bias[2];
  #pragma unroll
  for (int n = 0; n < 2; ++n)
    bias[n] = dpb[(size_t)e * HDIM + h0 + wn * 32 + n * 16 + ln15];
  #pragma unroll
  for (int m = 0; m < 5; ++m) {
    #pragma unroll
    for (int rg = 0; rg < 4; ++rg) {
      int row = wm * 80 + m * 16 + kq * 4 + rg;
      int r = rowid[row];
      if (r < 0) continue;
      float wgt = routing[r];
      #pragma unroll
      for (int n = 0; n < 2; ++n) {
        int hcol = h0 + wn * 32 + n * 16 + ln15;
        atomicAdd(outp + (size_t)(r >> 1) * HDIM + hcol,
                  wgt * (acc[m][n][rg] + bias[n]));
      }
    }
  }
}

// ---------- launch ----------

extern "C" void kernel_launch(void* const* d_in, const int* in_sizes, int n_in,
                              void* d_out, int out_size, void* d_ws, size_t ws_size,
                              hipStream_t stream) {
  const float* hidden  = (const float*)d_in[0];
  const float* routing = (const float*)d_in[1];
  const float* gub     = (const float*)d_in[2];
  const float* dpb     = (const float*)d_in[3];
  const int*   ridx    = (const int*)d_in[4];
  const int*   guq     = (const int*)d_in[5];
  const int*   gus     = (const int*)d_in[6];
  const int*   dq      = (const int*)d_in[7];
  const int*   dsc     = (const int*)d_in[8];
  float* outp = (float*)d_out;

  char* ws = (char*)d_ws;
  int* counts = (int*)ws;
  int* lists  = (int*)(ws + 256);
  const bool pre = (ws_size >= WS_NEED);
  const uint gatedOff = pre ? GATED_OFF_PRE : HB_OFF;
  ushort* hb    = (ushort*)(ws + HB_OFF);
  ushort* gated = (ushort*)(ws + gatedOff);

  hipMemsetAsync(counts, 0, 256, stream);
  hipMemsetAsync(ws + ZROW_OFF, 0, 8192, stream);
  hipMemsetAsync(d_out, 0, (size_t)out_size * sizeof(float), stream);

  build_lists_kernel<<<MAXR / 256, 256, 0, stream>>>(ridx, counts, lists);
  if (pre)
    cvt_kernel<<<(T_TOK * HDIM / 8) / 256, 256, 0, stream>>>(hidden, hb);

  const int mtiles = (MAXR + BM - 1) / BM;
  if (pre) {
    dim3 grid1((GU / 128) * NEXP, mtiles);
    gemm1_kernel<<<grid1, 512, 0, stream>>>(ws, guq, gus, gub, counts, lists, gated);
  } else {
    dim3 grid1f((GU / 64) * NEXP, mtiles);
    gemm1_fb<<<grid1f, 256, 0, stream>>>(hidden, guq, gus, gub, counts, lists, gated);
  }

  dim3 grid2((HDIM / 64) * NEXP, mtiles);
  gemm2_kernel<<<grid2, 512, 0, stream>>>(ws, gatedOff, dq, dsc, dpb, routing,
                                          counts, lists, outp);
}